// Round 11
// baseline (392.797 us; speedup 1.0000x reference)
//
#include <hip/hip_runtime.h>
#include <cstdint>

// Problem constants (fixed by setup_inputs: H=480, W=1024, S=32, margin=10, step=4)
#define HH 480
#define WW 1024
#define SS 32
#define HW (HH*WW)              // 491520
#define MARGIN 10
#define STEP 4
#define GYC 116                 // len(arange(10, 471, 4))
#define GXC 252                 // len(arange(10, 1015, 4))
#define GG (GYC*GXC)            // 29232 grid candidates (= 456*64 + 48)
#define NSLOT (2*HH*WW/(STEP*STEP))  // 61440 trajectory slots
#define NBLK (NSLOT/256)        // 240 blocks -> co-resident on 256 CUs
#define CW ((GG+63)/64)         // 457 candidate bitmap words
#define CWP 512                 // padded word count (per-block scan width + plane stride)
#define FPW 256                 // u64 flag entries per parity plane (packed, 8 lines)
#define CPB 122                 // producer cells per block (240*122 >= GG)

// Agent-scope (device-coherent) accessors.
__device__ __forceinline__ unsigned long long aload64(const unsigned long long* p) {
  return __hip_atomic_load(p, __ATOMIC_RELAXED, __HIP_MEMORY_SCOPE_AGENT);
}
__device__ __forceinline__ void astore64(unsigned long long* p, unsigned long long v) {
  __hip_atomic_store(p, v, __ATOMIC_RELAXED, __HIP_MEMORY_SCOPE_AGENT);
}
__device__ __forceinline__ void aor64(unsigned long long* p, unsigned long long v) {
  (void)__hip_atomic_fetch_or(p, v, __ATOMIC_RELAXED, __HIP_MEMORY_SCOPE_AGENT);
}

__device__ __forceinline__ int clampi(int v, int lo, int hi) {
  return v < lo ? lo : (v > hi ? hi : v);
}

// Paired corner load: bilinear footprints always read cols (x0i, x1i) with
// x1i = min(x0i+1, WW-1). One unaligned 8B load at bx = min(x0i, WW-2) gives
// v = (base[row*WW+bx], base[row*WW+bx+1]); then
//   c0 = base[row*WW+x0i] = (x0i==bx) ? v.x : v.y   (x0i=WW-1 -> bx+1)
//   c1 = base[row*WW+x1i] = v.y                      (x1i = bx+1 in ALL cases)
// Values bit-identical to the two scalar loads; halves gather instructions.
__device__ __forceinline__ void ld2(const float* __restrict__ base, int row, int xlo,
                                    float& c0, float& c1) {
  int bx = (xlo < WW - 1) ? xlo : (WW - 2);
  float2 v;
  __builtin_memcpy(&v, base + row * WW + bx, 8);
  c0 = (xlo == bx) ? v.x : v.y;
  c1 = v.y;
}

// ---------------------------------------------------------------------------
// K0: zero the 32 occupancy bit-planes + init both parity flag planes.
// ---------------------------------------------------------------------------
__global__ __launch_bounds__(256) void k_init(unsigned long long* __restrict__ flags,
                                              unsigned int* __restrict__ bmp32)
{
  int idx = blockIdx.x * 256 + threadIdx.x;
  if (idx < 32 * CWP * 2) bmp32[idx] = 0u;           // 32 planes x 512 u64
  if (idx < 256) {
    unsigned long long v = (idx < NBLK) ? 0ull : (0x7FFFFFFFull << 32); // pads: +inf
    flags[idx] = v;
    flags[FPW + idx] = v;
  }
}

// ---------------------------------------------------------------------------
// Bilinear footprint at (xs,ys). Identical float ops to the verified kernels.
// ---------------------------------------------------------------------------
struct Bil {
  int x0i, x1i, y0i, y1i;
  int i00, i01, i10, i11;
  float w00, w01, w10, w11;
};

__device__ __forceinline__ Bil mkbil(float xs, float ys) {
#pragma clang fp contract(off)
  float x0 = floorf(xs), y0 = floorf(ys);
  float wx1 = xs - x0, wx0 = 1.0f - wx1;
  float wy1 = ys - y0, wy0 = 1.0f - wy1;
  Bil b;
  b.x0i = clampi((int)x0, 0, WW - 1);
  b.x1i = b.x0i + 1 > WW - 1 ? WW - 1 : b.x0i + 1;
  b.y0i = clampi((int)y0, 0, HH - 1);
  b.y1i = b.y0i + 1 > HH - 1 ? HH - 1 : b.y0i + 1;
  b.i00 = b.y0i * WW + b.x0i; b.i01 = b.y0i * WW + b.x1i;
  b.i10 = b.y1i * WW + b.x0i; b.i11 = b.y1i * WW + b.x1i;
  b.w00 = wy0 * wx0; b.w01 = wy0 * wx1;
  b.w10 = wy1 * wx0; b.w11 = wy1 * wx1;
  return b;
}

// Fwd-bwd consistency bit from pre-gathered backward-flow corner values.
__device__ __forceinline__ float prune_val(float fx, float fy,
    float c00a, float c01a, float c10a, float c11a,
    float c00b, float c01b, float c10b, float c11b, const Bil& t)
{
#pragma clang fp contract(off)
  float bw0 = ((c00a * t.w00 + c01a * t.w01) + c10a * t.w10) + c11a * t.w11;
  float bw1 = ((c00b * t.w00 + c01b * t.w01) + c10b * t.w10) + c11b * t.w11;
  float t0 = fx + bw0, t1 = fy + bw1;
  float diff = sqrtf(t0 * t0 + t1 * t1);
  float magf = sqrtf(fx * fx + fy * fy);
  float magb = sqrtf(bw0 * bw0 + bw1 * bw1);
  float mag = 0.5f * (magf + magb);
  return (diff <= 0.01f * mag + 0.1f) ? 1.0f : 0.0f;
}

// Integer-cell first-transition outcome {xt,yt,choose} packed as u64
// (choose encoded as yt<0). Bit-identical to the verified mode-2 path.
__device__ __forceinline__ unsigned long long make_intadv(
    int pix, int piy, float fx, float fy, const float* __restrict__ bks)
{
#pragma clang fp contract(off)
  float xt = (float)pix + fx, yt = (float)piy + fy;
  Bil Bt = mkbil(xt, yt);
  const float* b0p = bks;
  const float* b1p = bks + HW;
  float o = prune_val(fx, fy,
                      b0p[Bt.i00], b0p[Bt.i01], b0p[Bt.i10], b0p[Bt.i11],
                      b1p[Bt.i00], b1p[Bt.i01], b1p[Bt.i10], b1p[Bt.i11], Bt);
  bool marg = (xt > (float)MARGIN) && (yt > (float)MARGIN) &&
              (xt < (float)(WW - MARGIN)) && (yt < (float)(HH - MARGIN));
  bool ch = marg && (o > 0.5f);
  unsigned lo = __float_as_uint(ch ? xt : 0.0f);
  unsigned hi = __float_as_uint(ch ? yt : -1.0f);
  return ((unsigned long long)hi << 32) | (unsigned long long)lo;
}

// ---------------------------------------------------------------------------
// K1: persistent scan, ONE grid barrier per step. Round-11 scheduling bundle
// (all arithmetic/ordering byte-identical; only who/when executes moves):
//  * OVERLAP REORDER: issue the 4 f-ld2 FIRST, run the producer's
//    non-blocking work while f is in flight, THEN advect + issue b-taps.
//    The f-wait no longer delays poll entry.
//  * ALL-WAVE POLL: every wave polls the 8 packed flag lines and computes
//    its own dead-rank prefix in-register from the payload butterfly
//    (every lane holds the totals) -> post-poll __syncthreads + ps4 LDS gone.
//  * Poll break via per-lane min4 + one __all (vs 6-shfl reduce per iter).
//  * DEFERRED X/Y row stores: post-birth (x,y) saved in regs, stored right
//    after the NEXT step's arrival store (off the pre-arrival drain).
// ---------------------------------------------------------------------------
__global__ __launch_bounds__(256, 1) void k_steps(
    const float* __restrict__ ff, const float* __restrict__ fbk,
    float* __restrict__ X, float* __restrict__ Y, float* __restrict__ Start,
    unsigned long long* __restrict__ bmp, unsigned long long* __restrict__ flags,
    unsigned long long* __restrict__ intadv)
{
#pragma clang fp contract(off)
  const int b = blockIdx.x;
  const int lane = threadIdx.x & 63;
  const int wv = threadIdx.x >> 6;                   // wave-in-block 0..3
  const int slot = ((wv * NBLK + b) << 6) | lane;    // wave-permuted slot id
  const unsigned long long ltmask = (1ull << lane) - 1ull;

  __shared__ unsigned long long wds[CWP];   // free-candidate bitmap (4 KB)
  __shared__ unsigned int pref[CWP];        // inclusive popcount prefix (2 KB)
  __shared__ int wsum[4];                   // scan partials
  __shared__ int wcnt[2][4];                // per-wave dead counts (parity)

  // Consumer slot state. mode: 0 dead, 1 pipelined, 2 integer-pos (pa64 valid).
  float x = 0.f, y = 0.f, st = -1.f;
  int mode = 0;
  float pf0 = 0.f, pf1 = 0.f, pf2 = 0.f, pf3 = 0.f;   // f0 at taps 00,01,10,11
  float pf4 = 0.f, pf5 = 0.f, pf6 = 0.f, pf7 = 0.f;   // f1 at taps 00,01,10,11
  float pb[32];                                        // b corner values, 8/tap
  float pxt = 0.f, pyt = 0.f;                          // advected candidate
  bool  pmarg = false;
  unsigned long long pa64 = (unsigned long long)0xBF800000u << 32;  // yt=-1

  // Producer identity (decoupled from slot): even threads, ~30 cells/wave.
  const int pj = threadIdx.x >> 1;
  const int pcell = b * CPB + pj;
  const bool prod = ((threadIdx.x & 1) == 0) && (pj < CPB) && (pcell < GG);
  int pix = 0, piy = 0, pp = 0;
  float fNx = 0.f, fNy = 0.f;      // f(s+4) pair (issued last step)
  float fCx = 0.f, fCy = 0.f;      // f(s+3) pair (arrived)
  float bC0 = 0.f, bC1 = 0.f, bC2 = 0.f, bC3 = 0.f;   // b(s+3) corners
  float bC4 = 0.f, bC5 = 0.f, bC6 = 0.f, bC7 = 0.f;

  // ---- Slot prologue: initial alive slots compute their own A(0) input ----
  if (slot < GG) {
    int ii = slot / GXC, jj = slot - ii * GXC;
    int ix = MARGIN + STEP * jj, iy = MARGIN + STEP * ii;
    x = (float)ix; y = (float)iy;
    st = 0.f; mode = 2;
    int p0_ = iy * WW + ix;
    float f0x = ff[p0_], f0y = ff[HW + p0_];
    pa64 = make_intadv(ix, iy, f0x, f0y, fbk);
  }
  X[slot] = x; Y[slot] = y;   // row 0
  float rx = x, ry = y;       // deferred-store copy of the last-written row

  // ---- Producer prologue: bootstrap intadv[1..2] + b(3)/f(4) in flight ----
  if (prod) {
    int ii = pcell / GXC, jj = pcell - ii * GXC;
    pix = MARGIN + STEP * jj; piy = MARGIN + STEP * ii;
    pp = piy * WW + pix;
    float f1x = ff[(size_t)1 * 2 * HW + pp], f1y = ff[(size_t)1 * 2 * HW + HW + pp];
    float f2x = ff[(size_t)2 * 2 * HW + pp], f2y = ff[(size_t)2 * 2 * HW + HW + pp];
    float f3x = ff[(size_t)3 * 2 * HW + pp], f3y = ff[(size_t)3 * 2 * HW + HW + pp];
    fNx = ff[(size_t)4 * 2 * HW + pp];       fNy = ff[(size_t)4 * 2 * HW + HW + pp];
    astore64(&intadv[(size_t)1 * GG + pcell],
             make_intadv(pix, piy, f1x, f1y, fbk + (size_t)1 * 2 * HW));
    astore64(&intadv[(size_t)2 * GG + pcell],
             make_intadv(pix, piy, f2x, f2y, fbk + (size_t)2 * 2 * HW));
    {  // issue b(3) corners; consumed at overlap(0)
      float xt = (float)pix + f3x, yt = (float)piy + f3y;
      Bil Bt = mkbil(xt, yt);
      const float* bb0 = fbk + (size_t)3 * 2 * HW;
      const float* bb1 = bb0 + HW;
      ld2(bb0, Bt.y0i, Bt.x0i, bC0, bC1);
      ld2(bb0, Bt.y1i, Bt.x0i, bC2, bC3);
      ld2(bb1, Bt.y0i, Bt.x0i, bC4, bC5);
      ld2(bb1, Bt.y1i, Bt.x0i, bC6, bC7);
      fCx = f3x; fCy = f3y;
    }
  }

// Issue the 16 paired b-corner loads for tap tt (consumed next step's A).
#define ISSUE_TAP(tt, TXI, TYI, FX, FY) do { \
    Bil Bt = mkbil((float)P.TXI + (FX), (float)P.TYI + (FY)); \
    ld2(b0n, Bt.y0i, Bt.x0i, pb[(tt)*8+0], pb[(tt)*8+1]); \
    ld2(b0n, Bt.y1i, Bt.x0i, pb[(tt)*8+2], pb[(tt)*8+3]); \
    ld2(b1n, Bt.y0i, Bt.x0i, pb[(tt)*8+4], pb[(tt)*8+5]); \
    ld2(b1n, Bt.y1i, Bt.x0i, pb[(tt)*8+6], pb[(tt)*8+7]); \
  } while (0)

// Recompute the identical footprint and fold pre-loaded values into the bit.
#define PRUNE_TAP(tt, TXI, TYI, FX, FY, OUT) do { \
    Bil Bt = mkbil((float)P.TXI + (FX), (float)P.TYI + (FY)); \
    OUT = prune_val((FX), (FY), \
                    pb[(tt)*8+0], pb[(tt)*8+1], pb[(tt)*8+2], pb[(tt)*8+3], \
                    pb[(tt)*8+4], pb[(tt)*8+5], pb[(tt)*8+6], pb[(tt)*8+7], Bt); \
  } while (0)

  for (int s = 0; s < SS - 1; ++s) {
    unsigned long long* pl = bmp + (size_t)(s + 1) * CWP;   // this step's bit-plane

    // ---- Phase A: LOAD-FREE prune decision + bit-plane marks -------------
    bool moved = false;
    if (mode == 1) {
      Bil P = mkbil(x, y);
      float o0, o1, o2, o3;
      PRUNE_TAP(0, x0i, y0i, pf0, pf4, o0);
      PRUNE_TAP(1, x1i, y0i, pf1, pf5, o1);
      PRUNE_TAP(2, x0i, y1i, pf2, pf6, o2);
      PRUNE_TAP(3, x1i, y1i, pf3, pf7, o3);
      float fbv = ((o0 * P.w00 + o1 * P.w01) + o2 * P.w10) + o3 * P.w11;
      if (pmarg && fbv > 0.5f) {
        x = pxt; y = pyt;
        moved = true;
      } else { st = -1.f; x = 0.f; y = 0.f; mode = 0; }
    } else if (mode == 2) {
      float axt = __uint_as_float((unsigned)pa64);
      float ayt = __uint_as_float((unsigned)(pa64 >> 32));
      if (ayt >= 0.0f) {                      // choose
        x = axt; y = ayt; mode = 1;
        moved = true;
      } else { st = -1.f; x = 0.f; y = 0.f; mode = 0; }
    }
    if (moved) {
      int oy = (int)y, ox = (int)x;   // trunc == floor (positive)
      int i0 = ((oy - (MARGIN + 2) + 4099) >> 2) - 1024;  // ceil((oy-12)/4)
      int i1 = ((oy - (MARGIN - 2) + 4096) >> 2) - 1024;  // floor((oy-8)/4)
      int j0 = ((ox - (MARGIN + 2) + 4099) >> 2) - 1024;
      int j1 = ((ox - (MARGIN - 2) + 4096) >> 2) - 1024;
      if (i0 < 0) i0 = 0; if (i1 > GYC - 1) i1 = GYC - 1;
      if (j0 < 0) j0 = 0; if (j1 > GXC - 1) j1 = GXC - 1;
      for (int i = i0; i <= i1; ++i) {        // <=2 rows, <=2 adjacent bits
        int g0 = i * GXC + j0;
        int w = g0 >> 6, bo = g0 & 63;
        unsigned long long m = ((j1 > j0) ? 3ull : 1ull) << bo;  // bit63 ovfl drops
        aor64(&pl[w], m);
        if (bo == 63 && j1 > j0) aor64(&pl[w + 1], 1ull);
      }
    }
    unsigned long long smask = __ballot(st < 0.0f);
    if (lane == 0) wcnt[s & 1][wv] = (int)__popcll(smask);

    // ---- Barrier arrival: entry sync drains the marks, then one store ----
    unsigned long long* fb = flags + (s & 1) * FPW;
    const int epoch = s + 1;
    __syncthreads();
    if (threadIdx.x == 0) {
      const int* wc = wcnt[s & 1];
      unsigned cpack = (unsigned)wc[0] | ((unsigned)wc[1] << 8)
                     | ((unsigned)wc[2] << 16) | ((unsigned)wc[3] << 24);
      astore64(&fb[b],
               ((unsigned long long)(unsigned)epoch << 32) | (unsigned long long)cpack);
    }

    // ---- Deferred output store of row s (saved last iteration) -----------
    X[(size_t)s * NSLOT + slot] = rx;   // s=0 re-stores row 0: harmless dup
    Y[(size_t)s * NSLOT + slot] = ry;

    // ---- Wait-window overlap -------------------------------------------
    // (1) issue the 4 f(s+1) paired loads (non-blocking)
    const bool dopipe = (mode == 1 && s < SS - 2);
    Bil P;
    const float* f0n = ff + (size_t)(s + 1) * 2 * HW;
    const float* f1n = f0n + HW;
    if (dopipe) {
      P = mkbil(x, y);
      ld2(f0n, P.y0i, P.x0i, pf0, pf1);
      ld2(f0n, P.y1i, P.x0i, pf2, pf3);
      ld2(f1n, P.y0i, P.x0i, pf4, pf5);
      ld2(f1n, P.y1i, P.x0i, pf6, pf7);
    }
    // (2) producer work rides under the f-load latency
    if (prod) {
      if (s <= SS - 5) {                       // k = s+3 <= 30
        float xt = (float)pix + fCx, yt = (float)piy + fCy;
        Bil Bt = mkbil(xt, yt);
        float o = prune_val(fCx, fCy, bC0, bC1, bC2, bC3, bC4, bC5, bC6, bC7, Bt);
        bool marg = (xt > (float)MARGIN) && (yt > (float)MARGIN) &&
                    (xt < (float)(WW - MARGIN)) && (yt < (float)(HH - MARGIN));
        bool ch = marg && (o > 0.5f);
        unsigned lo = __float_as_uint(ch ? xt : 0.0f);
        unsigned hi = __float_as_uint(ch ? yt : -1.0f);
        astore64(&intadv[(size_t)(s + 3) * GG + pcell],
                 ((unsigned long long)hi << 32) | (unsigned long long)lo);
      }
      if (s <= SS - 6) {                       // issue b(s+4), f(s+4) arrived
        float xt = (float)pix + fNx, yt = (float)piy + fNy;
        Bil Bt = mkbil(xt, yt);
        const float* bb0 = fbk + (size_t)(s + 4) * 2 * HW;
        const float* bb1 = bb0 + HW;
        ld2(bb0, Bt.y0i, Bt.x0i, bC0, bC1);
        ld2(bb0, Bt.y1i, Bt.x0i, bC2, bC3);
        ld2(bb1, Bt.y0i, Bt.x0i, bC4, bC5);
        ld2(bb1, Bt.y1i, Bt.x0i, bC6, bC7);
        fCx = fNx; fCy = fNy;
      }
      if (s <= SS - 7) {                       // issue static f(s+5)
        const float* fp_ = ff + (size_t)(s + 5) * 2 * HW;
        fNx = fp_[pp]; fNy = fp_[HW + pp];
      }
    }
    // (3) consume pf: advect + issue the 16 b(s+1) paired loads
    if (dopipe) {
      float u_ = ((pf0 * P.w00 + pf1 * P.w01) + pf2 * P.w10) + pf3 * P.w11;
      float v_ = ((pf4 * P.w00 + pf5 * P.w01) + pf6 * P.w10) + pf7 * P.w11;
      pxt = x + u_; pyt = y + v_;
      pmarg = (pxt > (float)MARGIN) && (pyt > (float)MARGIN) &&
              (pxt < (float)(WW - MARGIN)) && (pyt < (float)(HH - MARGIN));
      const float* b0n = fbk + (size_t)(s + 1) * 2 * HW;
      const float* b1n = b0n + HW;
      ISSUE_TAP(0, x0i, y0i, pf0, pf4);
      ISSUE_TAP(1, x1i, y0i, pf1, pf5);
      ISSUE_TAP(2, x0i, y1i, pf2, pf6);
      ISSUE_TAP(3, x1i, y1i, pf3, pf7);
    }

    // ---- Poll (ALL waves): 4 loads/lane over 8 packed lines --------------
    int ps;
    {
      unsigned long long v0, v1, v2, v3;
      for (;;) {
        v0 = aload64(&fb[lane      ]);
        v1 = aload64(&fb[lane +  64]);
        v2 = aload64(&fb[lane + 128]);
        v3 = aload64(&fb[lane + 192]);
        unsigned m0 = (unsigned)(v0 >> 32), m1 = (unsigned)(v1 >> 32);
        unsigned m2 = (unsigned)(v2 >> 32), m3 = (unsigned)(v3 >> 32);
        unsigned mn = m0 < m1 ? m0 : m1;
        unsigned mn2 = m2 < m3 ? m2 : m3;
        mn = mn < mn2 ? mn : mn2;
        if (__all((int)mn >= epoch)) break;
        __builtin_amdgcn_s_sleep(1);
      }
      // unpack 4x8 -> 4x16 packed u64 (field sums <= 240*64 = 15360 < 65536)
      auto up = [](unsigned long long f) -> unsigned long long {
        unsigned c = (unsigned)f;
        return (unsigned long long)(c & 0xFFu)
             | ((unsigned long long)((c >>  8) & 0xFFu) << 16)
             | ((unsigned long long)((c >> 16) & 0xFFu) << 32)
             | ((unsigned long long)((c >> 24) & 0xFFu) << 48);
      };
      unsigned long long u0 = up(v0), u1 = up(v1), u2 = up(v2), u3 = up(v3);
      unsigned long long F = u0 + u1 + u2 + u3;
      unsigned long long Pp = (lane       < b ? u0 : 0ull)
                            + (lane +  64 < b ? u1 : 0ull)
                            + (lane + 128 < b ? u2 : 0ull)
                            + (lane + 192 < b ? u3 : 0ull);
      for (int o = 32; o > 0; o >>= 1) {
        unsigned flo = (unsigned)F, fhi = (unsigned)(F >> 32);
        unsigned plo = (unsigned)Pp, phi = (unsigned)(Pp >> 32);
        unsigned flo2 = (unsigned)__shfl_xor((int)flo, o, 64);
        unsigned fhi2 = (unsigned)__shfl_xor((int)fhi, o, 64);
        unsigned plo2 = (unsigned)__shfl_xor((int)plo, o, 64);
        unsigned phi2 = (unsigned)__shfl_xor((int)phi, o, 64);
        F  += ((unsigned long long)fhi2 << 32) | flo2;
        Pp += ((unsigned long long)phi2 << 32) | plo2;
      }
      // every lane now holds the totals; extract this wave's rank prefix
      int f0 = (int)(F & 0xFFFF), f1 = (int)((F >> 16) & 0xFFFF);
      int f2 = (int)((F >> 32) & 0xFFFF);
      int pw = (int)((Pp >> (16 * wv)) & 0xFFFF);
      ps = pw + ((wv > 0) ? f0 : 0) + ((wv > 1) ? f1 : 0) + ((wv > 2) ? f2 : 0);
    }

    // ---- Phase CD: direct masked bit-plane load + prefix + births --------
    {
      int t = threadIdx.x;
      int e0 = 2 * t, e1 = 2 * t + 1;
      unsigned long long m0 = 0ull, m1 = 0ull;
      if (e0 < CW) m0 = ~aload64(&pl[e0]);            // free = NOT occupied
      if (e1 < CW) m1 = ~aload64(&pl[e1]);
      if (e0 == CW - 1) m0 &= (1ull << 48) - 1ull;    // tail: 48 valid cells
      if (e1 == CW - 1) m1 &= (1ull << 48) - 1ull;
      wds[e0] = m0; wds[e1] = m1;
      int p0 = __popcll(m0), p1 = __popcll(m1);
      int v = p0 + p1;
      for (int o = 1; o < 64; o <<= 1) {
        int uu = __shfl_up(v, o, 64);
        if (lane >= o) v += uu;
      }
      if (lane == 63) wsum[wv] = v;
      __syncthreads();
      int base = 0;
      for (int j2 = 0; j2 < wv; ++j2) base += wsum[j2];
      pref[e0] = (unsigned int)(base + v - p1);
      pref[e1] = (unsigned int)(base + v);
      __syncthreads();
    }
    int tc = (int)pref[CWP - 1];              // total free candidates

    if (st < 0.0f) {
      int r = ps + (int)__popcll(smask & ltmask);
      if (r < tc) {                  // r < min(num_cand, num_free) <=> r < num_cand
        int k = 0;
        for (int bb = 256; bb >= 1; bb >>= 1) {
          int nk = k + bb;
          if (nk <= CWP - 1 && (int)pref[nk - 1] <= r) k = nk;
        }
        int j = r - (k ? (int)pref[k - 1] : 0);
        unsigned long long m = wds[k];
        int lo = 0;                  // position of the (j+1)-th set bit
        for (int bb = 32; bb >= 1; bb >>= 1) {
          int nb2 = lo + bb;
          unsigned long long mask = (nb2 >= 64) ? ~0ull : ((1ull << nb2) - 1ull);
          if (__popcll(m & mask) <= j) lo = nb2;
        }
        int g = k * 64 + lo;
        int ii = g / GXC, jj = g - ii * GXC;
        x = (float)(MARGIN + STEP * jj);
        y = (float)(MARGIN + STEP * ii);
        st = (float)(s + 1);
        mode = 2;
        if (s < SS - 2)              // at s=30 there is no A(31): skip the load
          pa64 = aload64(&intadv[(size_t)(s + 1) * GG + g]);   // in flight to A(s+1)
      }
    }
    rx = x; ry = y;   // row s+1 values; stored after next iteration's arrival
    // no trailing __syncthreads: wcnt is parity-double-buffered; wds/pref
    // rewrites happen only after the next step's entry __syncthreads.
  }

#undef ISSUE_TAP
#undef PRUNE_TAP

  X[(size_t)(SS - 1) * NSLOT + slot] = rx;   // final row (31)
  Y[(size_t)(SS - 1) * NSLOT + slot] = ry;
  Start[slot] = st;
}

// ---------------------------------------------------------------------------
extern "C" void kernel_launch(void* const* d_in, const int* in_sizes, int n_in,
                              void* d_out, int out_size, void* d_ws, size_t ws_size,
                              hipStream_t stream) {
  const float* ff  = (const float*)d_in[0];   // (1,S,2,H,W)
  const float* fbk = (const float*)d_in[1];

  float* X     = (float*)d_out;                       // (S, N)
  float* Y     = X + (size_t)SS * NSLOT;              // (S, N)
  float* Start = Y + (size_t)SS * NSLOT;              // (N,)

  unsigned long long* flags  = (unsigned long long*)d_ws;              // 4 KB
  unsigned long long* bmp    = flags + 2 * FPW;                        // 32 planes x 512 u64
  unsigned long long* intadv = bmp + 32 * CWP;                         // 31*GG u64

  k_init<<<128, 256, 0, stream>>>(flags, (unsigned int*)bmp);

  k_steps<<<NBLK, 256, 0, stream>>>(ff, fbk, X, Y, Start, bmp, flags, intadv);
}

// Round 12
// 378.081 us; speedup vs baseline: 1.0389x; 1.0389x over previous
//
#include <hip/hip_runtime.h>
#include <cstdint>

// Problem constants (fixed by setup_inputs: H=480, W=1024, S=32, margin=10, step=4)
#define HH 480
#define WW 1024
#define SS 32
#define HW (HH*WW)              // 491520
#define MARGIN 10
#define STEP 4
#define GYC 116                 // len(arange(10, 471, 4))
#define GXC 252                 // len(arange(10, 1015, 4))
#define GG (GYC*GXC)            // 29232 grid candidates (= 456*64 + 48)
#define NSLOT (2*HH*WW/(STEP*STEP))  // 61440 trajectory slots
#define NBLK (NSLOT/256)        // 240 blocks -> co-resident on 256 CUs
#define CW ((GG+63)/64)         // 457 candidate bitmap words
#define CWP 512                 // padded word count (per-block scan width + plane stride)
#define FPW 256                 // u64 flag entries per parity plane (packed, 8 lines)
#define CPB 122                 // producer cells per block (240*122 >= GG)

// Agent-scope (device-coherent) accessors.
__device__ __forceinline__ unsigned long long aload64(const unsigned long long* p) {
  return __hip_atomic_load(p, __ATOMIC_RELAXED, __HIP_MEMORY_SCOPE_AGENT);
}
__device__ __forceinline__ void astore64(unsigned long long* p, unsigned long long v) {
  __hip_atomic_store(p, v, __ATOMIC_RELAXED, __HIP_MEMORY_SCOPE_AGENT);
}
__device__ __forceinline__ void aor64(unsigned long long* p, unsigned long long v) {
  (void)__hip_atomic_fetch_or(p, v, __ATOMIC_RELAXED, __HIP_MEMORY_SCOPE_AGENT);
}

__device__ __forceinline__ int clampi(int v, int lo, int hi) {
  return v < lo ? lo : (v > hi ? hi : v);
}

// Paired corner load: bilinear footprints always read cols (x0i, x1i) with
// x1i = min(x0i+1, WW-1). One unaligned 8B load at bx = min(x0i, WW-2) gives
// v = (base[row*WW+bx], base[row*WW+bx+1]); then
//   c0 = base[row*WW+x0i] = (x0i==bx) ? v.x : v.y   (x0i=WW-1 -> bx+1)
//   c1 = base[row*WW+x1i] = v.y                      (x1i = bx+1 in ALL cases)
// Values bit-identical to the two scalar loads; halves gather instructions.
__device__ __forceinline__ void ld2(const float* __restrict__ base, int row, int xlo,
                                    float& c0, float& c1) {
  int bx = (xlo < WW - 1) ? xlo : (WW - 2);
  float2 v;
  __builtin_memcpy(&v, base + row * WW + bx, 8);
  c0 = (xlo == bx) ? v.x : v.y;
  c1 = v.y;
}

// ---------------------------------------------------------------------------
// K0: zero the 32 occupancy bit-planes + init both parity flag planes.
// ---------------------------------------------------------------------------
__global__ __launch_bounds__(256) void k_init(unsigned long long* __restrict__ flags,
                                              unsigned int* __restrict__ bmp32)
{
  int idx = blockIdx.x * 256 + threadIdx.x;
  if (idx < 32 * CWP * 2) bmp32[idx] = 0u;           // 32 planes x 512 u64
  if (idx < 256) {
    unsigned long long v = (idx < NBLK) ? 0ull : (0x7FFFFFFFull << 32); // pads: +inf
    flags[idx] = v;
    flags[FPW + idx] = v;
  }
}

// ---------------------------------------------------------------------------
// Bilinear footprint at (xs,ys). Identical float ops to the verified kernels.
// ---------------------------------------------------------------------------
struct Bil {
  int x0i, x1i, y0i, y1i;
  int i00, i01, i10, i11;
  float w00, w01, w10, w11;
};

__device__ __forceinline__ Bil mkbil(float xs, float ys) {
#pragma clang fp contract(off)
  float x0 = floorf(xs), y0 = floorf(ys);
  float wx1 = xs - x0, wx0 = 1.0f - wx1;
  float wy1 = ys - y0, wy0 = 1.0f - wy1;
  Bil b;
  b.x0i = clampi((int)x0, 0, WW - 1);
  b.x1i = b.x0i + 1 > WW - 1 ? WW - 1 : b.x0i + 1;
  b.y0i = clampi((int)y0, 0, HH - 1);
  b.y1i = b.y0i + 1 > HH - 1 ? HH - 1 : b.y0i + 1;
  b.i00 = b.y0i * WW + b.x0i; b.i01 = b.y0i * WW + b.x1i;
  b.i10 = b.y1i * WW + b.x0i; b.i11 = b.y1i * WW + b.x1i;
  b.w00 = wy0 * wx0; b.w01 = wy0 * wx1;
  b.w10 = wy1 * wx0; b.w11 = wy1 * wx1;
  return b;
}

// Fwd-bwd consistency bit from pre-gathered backward-flow corner values.
__device__ __forceinline__ float prune_val(float fx, float fy,
    float c00a, float c01a, float c10a, float c11a,
    float c00b, float c01b, float c10b, float c11b, const Bil& t)
{
#pragma clang fp contract(off)
  float bw0 = ((c00a * t.w00 + c01a * t.w01) + c10a * t.w10) + c11a * t.w11;
  float bw1 = ((c00b * t.w00 + c01b * t.w01) + c10b * t.w10) + c11b * t.w11;
  float t0 = fx + bw0, t1 = fy + bw1;
  float diff = sqrtf(t0 * t0 + t1 * t1);
  float magf = sqrtf(fx * fx + fy * fy);
  float magb = sqrtf(bw0 * bw0 + bw1 * bw1);
  float mag = 0.5f * (magf + magb);
  return (diff <= 0.01f * mag + 0.1f) ? 1.0f : 0.0f;
}

// Integer-cell first-transition outcome {xt,yt,choose} packed as u64
// (choose encoded as yt<0). Bit-identical to the verified mode-2 path.
__device__ __forceinline__ unsigned long long make_intadv(
    int pix, int piy, float fx, float fy, const float* __restrict__ bks)
{
#pragma clang fp contract(off)
  float xt = (float)pix + fx, yt = (float)piy + fy;
  Bil Bt = mkbil(xt, yt);
  const float* b0p = bks;
  const float* b1p = bks + HW;
  float o = prune_val(fx, fy,
                      b0p[Bt.i00], b0p[Bt.i01], b0p[Bt.i10], b0p[Bt.i11],
                      b1p[Bt.i00], b1p[Bt.i01], b1p[Bt.i10], b1p[Bt.i11], Bt);
  bool marg = (xt > (float)MARGIN) && (yt > (float)MARGIN) &&
              (xt < (float)(WW - MARGIN)) && (yt < (float)(HH - MARGIN));
  bool ch = marg && (o > 0.5f);
  unsigned lo = __float_as_uint(ch ? xt : 0.0f);
  unsigned hi = __float_as_uint(ch ? yt : -1.0f);
  return ((unsigned long long)hi << 32) | (unsigned long long)lo;
}

// ---------------------------------------------------------------------------
// K1: persistent scan, ONE grid barrier per step. Round-12 = verified
// round-10 kernel + EXACTLY ONE change from the round-11 bundle (which
// regressed 203->222 by bundling all-wave poll contention):
//  * OVERLAP REORDER only: issue the 4 f-ld2 FIRST, run the producer's
//    work while f is in flight, THEN advect + issue b-taps. The f-load
//    wait no longer delays poll entry. Wave-0-only poll, ps4 LDS handoff,
//    and immediate X/Y row stores are all restored to round-10 form.
// ---------------------------------------------------------------------------
__global__ __launch_bounds__(256, 1) void k_steps(
    const float* __restrict__ ff, const float* __restrict__ fbk,
    float* __restrict__ X, float* __restrict__ Y, float* __restrict__ Start,
    unsigned long long* __restrict__ bmp, unsigned long long* __restrict__ flags,
    unsigned long long* __restrict__ intadv)
{
#pragma clang fp contract(off)
  const int b = blockIdx.x;
  const int lane = threadIdx.x & 63;
  const int wv = threadIdx.x >> 6;                   // wave-in-block 0..3
  const int slot = ((wv * NBLK + b) << 6) | lane;    // wave-permuted slot id
  const unsigned long long ltmask = (1ull << lane) - 1ull;

  __shared__ unsigned long long wds[CWP];   // free-candidate bitmap (4 KB)
  __shared__ unsigned int pref[CWP];        // inclusive popcount prefix (2 KB)
  __shared__ int wsum[4];                   // scan partials
  __shared__ int wcnt[2][4];                // per-wave dead counts (parity)
  __shared__ int ps4[4];                    // per-wave lower-rank totals

  // Consumer slot state. mode: 0 dead, 1 pipelined, 2 integer-pos (pa64 valid).
  float x = 0.f, y = 0.f, st = -1.f;
  int mode = 0;
  float pf0 = 0.f, pf1 = 0.f, pf2 = 0.f, pf3 = 0.f;   // f0 at taps 00,01,10,11
  float pf4 = 0.f, pf5 = 0.f, pf6 = 0.f, pf7 = 0.f;   // f1 at taps 00,01,10,11
  float pb[32];                                        // b corner values, 8/tap
  float pxt = 0.f, pyt = 0.f;                          // advected candidate
  bool  pmarg = false;
  unsigned long long pa64 = (unsigned long long)0xBF800000u << 32;  // yt=-1

  // Producer identity (decoupled from slot): even threads, ~30 cells/wave.
  const int pj = threadIdx.x >> 1;
  const int pcell = b * CPB + pj;
  const bool prod = ((threadIdx.x & 1) == 0) && (pj < CPB) && (pcell < GG);
  int pix = 0, piy = 0, pp = 0;
  float fNx = 0.f, fNy = 0.f;      // f(s+4) pair (issued last step)
  float fCx = 0.f, fCy = 0.f;      // f(s+3) pair (arrived)
  float bC0 = 0.f, bC1 = 0.f, bC2 = 0.f, bC3 = 0.f;   // b(s+3) corners
  float bC4 = 0.f, bC5 = 0.f, bC6 = 0.f, bC7 = 0.f;

  // ---- Slot prologue: initial alive slots compute their own A(0) input ----
  if (slot < GG) {
    int ii = slot / GXC, jj = slot - ii * GXC;
    int ix = MARGIN + STEP * jj, iy = MARGIN + STEP * ii;
    x = (float)ix; y = (float)iy;
    st = 0.f; mode = 2;
    int p0_ = iy * WW + ix;
    float f0x = ff[p0_], f0y = ff[HW + p0_];
    pa64 = make_intadv(ix, iy, f0x, f0y, fbk);
  }
  X[slot] = x; Y[slot] = y;   // row 0

  // ---- Producer prologue: bootstrap intadv[1..2] + b(3)/f(4) in flight ----
  if (prod) {
    int ii = pcell / GXC, jj = pcell - ii * GXC;
    pix = MARGIN + STEP * jj; piy = MARGIN + STEP * ii;
    pp = piy * WW + pix;
    float f1x = ff[(size_t)1 * 2 * HW + pp], f1y = ff[(size_t)1 * 2 * HW + HW + pp];
    float f2x = ff[(size_t)2 * 2 * HW + pp], f2y = ff[(size_t)2 * 2 * HW + HW + pp];
    float f3x = ff[(size_t)3 * 2 * HW + pp], f3y = ff[(size_t)3 * 2 * HW + HW + pp];
    fNx = ff[(size_t)4 * 2 * HW + pp];       fNy = ff[(size_t)4 * 2 * HW + HW + pp];
    astore64(&intadv[(size_t)1 * GG + pcell],
             make_intadv(pix, piy, f1x, f1y, fbk + (size_t)1 * 2 * HW));
    astore64(&intadv[(size_t)2 * GG + pcell],
             make_intadv(pix, piy, f2x, f2y, fbk + (size_t)2 * 2 * HW));
    {  // issue b(3) corners; consumed at overlap(0)
      float xt = (float)pix + f3x, yt = (float)piy + f3y;
      Bil Bt = mkbil(xt, yt);
      const float* bb0 = fbk + (size_t)3 * 2 * HW;
      const float* bb1 = bb0 + HW;
      ld2(bb0, Bt.y0i, Bt.x0i, bC0, bC1);
      ld2(bb0, Bt.y1i, Bt.x0i, bC2, bC3);
      ld2(bb1, Bt.y0i, Bt.x0i, bC4, bC5);
      ld2(bb1, Bt.y1i, Bt.x0i, bC6, bC7);
      fCx = f3x; fCy = f3y;
    }
  }

// Issue the 16 paired b-corner loads for tap tt (consumed next step's A).
#define ISSUE_TAP(tt, TXI, TYI, FX, FY) do { \
    Bil Bt = mkbil((float)P.TXI + (FX), (float)P.TYI + (FY)); \
    ld2(b0n, Bt.y0i, Bt.x0i, pb[(tt)*8+0], pb[(tt)*8+1]); \
    ld2(b0n, Bt.y1i, Bt.x0i, pb[(tt)*8+2], pb[(tt)*8+3]); \
    ld2(b1n, Bt.y0i, Bt.x0i, pb[(tt)*8+4], pb[(tt)*8+5]); \
    ld2(b1n, Bt.y1i, Bt.x0i, pb[(tt)*8+6], pb[(tt)*8+7]); \
  } while (0)

// Recompute the identical footprint and fold pre-loaded values into the bit.
#define PRUNE_TAP(tt, TXI, TYI, FX, FY, OUT) do { \
    Bil Bt = mkbil((float)P.TXI + (FX), (float)P.TYI + (FY)); \
    OUT = prune_val((FX), (FY), \
                    pb[(tt)*8+0], pb[(tt)*8+1], pb[(tt)*8+2], pb[(tt)*8+3], \
                    pb[(tt)*8+4], pb[(tt)*8+5], pb[(tt)*8+6], pb[(tt)*8+7], Bt); \
  } while (0)

  for (int s = 0; s < SS - 1; ++s) {
    unsigned long long* pl = bmp + (size_t)(s + 1) * CWP;   // this step's bit-plane

    // ---- Phase A: LOAD-FREE prune decision + bit-plane marks -------------
    bool moved = false;
    if (mode == 1) {
      Bil P = mkbil(x, y);
      float o0, o1, o2, o3;
      PRUNE_TAP(0, x0i, y0i, pf0, pf4, o0);
      PRUNE_TAP(1, x1i, y0i, pf1, pf5, o1);
      PRUNE_TAP(2, x0i, y1i, pf2, pf6, o2);
      PRUNE_TAP(3, x1i, y1i, pf3, pf7, o3);
      float fbv = ((o0 * P.w00 + o1 * P.w01) + o2 * P.w10) + o3 * P.w11;
      if (pmarg && fbv > 0.5f) {
        x = pxt; y = pyt;
        moved = true;
      } else { st = -1.f; x = 0.f; y = 0.f; mode = 0; }
    } else if (mode == 2) {
      float axt = __uint_as_float((unsigned)pa64);
      float ayt = __uint_as_float((unsigned)(pa64 >> 32));
      if (ayt >= 0.0f) {                      // choose
        x = axt; y = ayt; mode = 1;
        moved = true;
      } else { st = -1.f; x = 0.f; y = 0.f; mode = 0; }
    }
    if (moved) {
      int oy = (int)y, ox = (int)x;   // trunc == floor (positive)
      int i0 = ((oy - (MARGIN + 2) + 4099) >> 2) - 1024;  // ceil((oy-12)/4)
      int i1 = ((oy - (MARGIN - 2) + 4096) >> 2) - 1024;  // floor((oy-8)/4)
      int j0 = ((ox - (MARGIN + 2) + 4099) >> 2) - 1024;
      int j1 = ((ox - (MARGIN - 2) + 4096) >> 2) - 1024;
      if (i0 < 0) i0 = 0; if (i1 > GYC - 1) i1 = GYC - 1;
      if (j0 < 0) j0 = 0; if (j1 > GXC - 1) j1 = GXC - 1;
      for (int i = i0; i <= i1; ++i) {        // <=2 rows, <=2 adjacent bits
        int g0 = i * GXC + j0;
        int w = g0 >> 6, bo = g0 & 63;
        unsigned long long m = ((j1 > j0) ? 3ull : 1ull) << bo;  // bit63 ovfl drops
        aor64(&pl[w], m);
        if (bo == 63 && j1 > j0) aor64(&pl[w + 1], 1ull);
      }
    }
    unsigned long long smask = __ballot(st < 0.0f);
    if (lane == 0) wcnt[s & 1][wv] = (int)__popcll(smask);

    // ---- Barrier arrival: entry sync drains the marks, then one store ----
    unsigned long long* fb = flags + (s & 1) * FPW;
    const int epoch = s + 1;
    __syncthreads();
    if (threadIdx.x == 0) {
      const int* wc = wcnt[s & 1];
      unsigned cpack = (unsigned)wc[0] | ((unsigned)wc[1] << 8)
                     | ((unsigned)wc[2] << 16) | ((unsigned)wc[3] << 24);
      astore64(&fb[b],
               ((unsigned long long)(unsigned)epoch << 32) | (unsigned long long)cpack);
    }

    // ---- Wait-window overlap (reordered: f-issue / producer / consume) ---
    // (1) issue the 4 f(s+1) paired loads (non-blocking)
    const bool dopipe = (mode == 1 && s < SS - 2);
    Bil P;
    const float* f0n = ff + (size_t)(s + 1) * 2 * HW;
    const float* f1n = f0n + HW;
    if (dopipe) {
      P = mkbil(x, y);
      ld2(f0n, P.y0i, P.x0i, pf0, pf1);
      ld2(f0n, P.y1i, P.x0i, pf2, pf3);
      ld2(f1n, P.y0i, P.x0i, pf4, pf5);
      ld2(f1n, P.y1i, P.x0i, pf6, pf7);
    }
    // (2) producer work rides under the f-load latency
    if (prod) {
      if (s <= SS - 5) {                       // k = s+3 <= 30
        float xt = (float)pix + fCx, yt = (float)piy + fCy;
        Bil Bt = mkbil(xt, yt);
        float o = prune_val(fCx, fCy, bC0, bC1, bC2, bC3, bC4, bC5, bC6, bC7, Bt);
        bool marg = (xt > (float)MARGIN) && (yt > (float)MARGIN) &&
                    (xt < (float)(WW - MARGIN)) && (yt < (float)(HH - MARGIN));
        bool ch = marg && (o > 0.5f);
        unsigned lo = __float_as_uint(ch ? xt : 0.0f);
        unsigned hi = __float_as_uint(ch ? yt : -1.0f);
        astore64(&intadv[(size_t)(s + 3) * GG + pcell],
                 ((unsigned long long)hi << 32) | (unsigned long long)lo);
      }
      if (s <= SS - 6) {                       // issue b(s+4), f(s+4) arrived
        float xt = (float)pix + fNx, yt = (float)piy + fNy;
        Bil Bt = mkbil(xt, yt);
        const float* bb0 = fbk + (size_t)(s + 4) * 2 * HW;
        const float* bb1 = bb0 + HW;
        ld2(bb0, Bt.y0i, Bt.x0i, bC0, bC1);
        ld2(bb0, Bt.y1i, Bt.x0i, bC2, bC3);
        ld2(bb1, Bt.y0i, Bt.x0i, bC4, bC5);
        ld2(bb1, Bt.y1i, Bt.x0i, bC6, bC7);
        fCx = fNx; fCy = fNy;
      }
      if (s <= SS - 7) {                       // issue static f(s+5)
        const float* fp_ = ff + (size_t)(s + 5) * 2 * HW;
        fNx = fp_[pp]; fNy = fp_[HW + pp];
      }
    }
    // (3) consume pf: advect + issue the 16 b(s+1) paired loads
    if (dopipe) {
      float u_ = ((pf0 * P.w00 + pf1 * P.w01) + pf2 * P.w10) + pf3 * P.w11;
      float v_ = ((pf4 * P.w00 + pf5 * P.w01) + pf6 * P.w10) + pf7 * P.w11;
      pxt = x + u_; pyt = y + v_;
      pmarg = (pxt > (float)MARGIN) && (pyt > (float)MARGIN) &&
              (pxt < (float)(WW - MARGIN)) && (pyt < (float)(HH - MARGIN));
      const float* b0n = fbk + (size_t)(s + 1) * 2 * HW;
      const float* b1n = b0n + HW;
      ISSUE_TAP(0, x0i, y0i, pf0, pf4);
      ISSUE_TAP(1, x1i, y0i, pf1, pf5);
      ISSUE_TAP(2, x0i, y1i, pf2, pf6);
      ISSUE_TAP(3, x1i, y1i, pf3, pf7);
    }

    // ---- Poll (wave 0): 4 loads/lane over 8 packed lines + rank prefix ---
    if (threadIdx.x < 64) {
      unsigned long long v0, v1, v2, v3;
      for (;;) {
        v0 = aload64(&fb[lane      ]);
        v1 = aload64(&fb[lane +  64]);
        v2 = aload64(&fb[lane + 128]);
        v3 = aload64(&fb[lane + 192]);
        unsigned m0 = (unsigned)(v0 >> 32), m1 = (unsigned)(v1 >> 32);
        unsigned m2 = (unsigned)(v2 >> 32), m3 = (unsigned)(v3 >> 32);
        unsigned mn = m0 < m1 ? m0 : m1;
        unsigned mn2 = m2 < m3 ? m2 : m3;
        mn = mn < mn2 ? mn : mn2;
        for (int o = 32; o > 0; o >>= 1) {
          unsigned t = (unsigned)__shfl_xor((int)mn, o, 64);
          mn = mn < t ? mn : t;
        }
        if ((int)mn >= epoch) break;
        __builtin_amdgcn_s_sleep(1);
      }
      auto up = [](unsigned long long f) -> unsigned long long {
        unsigned c = (unsigned)f;
        return (unsigned long long)(c & 0xFFu)
             | ((unsigned long long)((c >>  8) & 0xFFu) << 16)
             | ((unsigned long long)((c >> 16) & 0xFFu) << 32)
             | ((unsigned long long)((c >> 24) & 0xFFu) << 48);
      };
      unsigned long long u0 = up(v0), u1 = up(v1), u2 = up(v2), u3 = up(v3);
      unsigned long long F = u0 + u1 + u2 + u3;
      unsigned long long Pp = (lane       < b ? u0 : 0ull)
                            + (lane +  64 < b ? u1 : 0ull)
                            + (lane + 128 < b ? u2 : 0ull)
                            + (lane + 192 < b ? u3 : 0ull);
      for (int o = 32; o > 0; o >>= 1) {
        unsigned flo = (unsigned)F, fhi = (unsigned)(F >> 32);
        unsigned plo = (unsigned)Pp, phi = (unsigned)(Pp >> 32);
        unsigned flo2 = (unsigned)__shfl_xor((int)flo, o, 64);
        unsigned fhi2 = (unsigned)__shfl_xor((int)fhi, o, 64);
        unsigned plo2 = (unsigned)__shfl_xor((int)plo, o, 64);
        unsigned phi2 = (unsigned)__shfl_xor((int)phi, o, 64);
        F  += ((unsigned long long)fhi2 << 32) | flo2;
        Pp += ((unsigned long long)phi2 << 32) | plo2;
      }
      if (lane == 0) {
        int f0 = (int)(F & 0xFFFF), f1 = (int)((F >> 16) & 0xFFFF), f2 = (int)((F >> 32) & 0xFFFF);
        int p0 = (int)(Pp & 0xFFFF), p1 = (int)((Pp >> 16) & 0xFFFF);
        int p2 = (int)((Pp >> 32) & 0xFFFF), p3 = (int)((Pp >> 48) & 0xFFFF);
        ps4[0] = p0;
        ps4[1] = f0 + p1;
        ps4[2] = f0 + f1 + p2;
        ps4[3] = f0 + f1 + f2 + p3;
      }
    }
    __syncthreads();
    int ps = ps4[wv];

    // ---- Phase CD: direct masked bit-plane load + prefix + births --------
    {
      int t = threadIdx.x;
      int e0 = 2 * t, e1 = 2 * t + 1;
      unsigned long long m0 = 0ull, m1 = 0ull;
      if (e0 < CW) m0 = ~aload64(&pl[e0]);            // free = NOT occupied
      if (e1 < CW) m1 = ~aload64(&pl[e1]);
      if (e0 == CW - 1) m0 &= (1ull << 48) - 1ull;    // tail: 48 valid cells
      if (e1 == CW - 1) m1 &= (1ull << 48) - 1ull;
      wds[e0] = m0; wds[e1] = m1;
      int p0 = __popcll(m0), p1 = __popcll(m1);
      int v = p0 + p1;
      for (int o = 1; o < 64; o <<= 1) {
        int uu = __shfl_up(v, o, 64);
        if (lane >= o) v += uu;
      }
      if (lane == 63) wsum[wv] = v;
      __syncthreads();
      int base = 0;
      for (int j2 = 0; j2 < wv; ++j2) base += wsum[j2];
      pref[e0] = (unsigned int)(base + v - p1);
      pref[e1] = (unsigned int)(base + v);
      __syncthreads();
    }
    int tc = (int)pref[CWP - 1];              // total free candidates

    if (st < 0.0f) {
      int r = ps + (int)__popcll(smask & ltmask);
      if (r < tc) {                  // r < min(num_cand, num_free) <=> r < num_cand
        int k = 0;
        for (int bb = 256; bb >= 1; bb >>= 1) {
          int nk = k + bb;
          if (nk <= CWP - 1 && (int)pref[nk - 1] <= r) k = nk;
        }
        int j = r - (k ? (int)pref[k - 1] : 0);
        unsigned long long m = wds[k];
        int lo = 0;                  // position of the (j+1)-th set bit
        for (int bb = 32; bb >= 1; bb >>= 1) {
          int nb2 = lo + bb;
          unsigned long long mask = (nb2 >= 64) ? ~0ull : ((1ull << nb2) - 1ull);
          if (__popcll(m & mask) <= j) lo = nb2;
        }
        int g = k * 64 + lo;
        int ii = g / GXC, jj = g - ii * GXC;
        x = (float)(MARGIN + STEP * jj);
        y = (float)(MARGIN + STEP * ii);
        st = (float)(s + 1);
        mode = 2;
        if (s < SS - 2)              // at s=30 there is no A(31): skip the load
          pa64 = aload64(&intadv[(size_t)(s + 1) * GG + g]);   // in flight to A(s+1)
      }
    }
    X[(size_t)(s + 1) * NSLOT + slot] = x;
    Y[(size_t)(s + 1) * NSLOT + slot] = y;
    // no trailing __syncthreads: wcnt is parity-double-buffered, and wds/pref
    // rewrites happen only after the next step's post-poll __syncthreads.
  }

#undef ISSUE_TAP
#undef PRUNE_TAP

  Start[slot] = st;
}

// ---------------------------------------------------------------------------
extern "C" void kernel_launch(void* const* d_in, const int* in_sizes, int n_in,
                              void* d_out, int out_size, void* d_ws, size_t ws_size,
                              hipStream_t stream) {
  const float* ff  = (const float*)d_in[0];   // (1,S,2,H,W)
  const float* fbk = (const float*)d_in[1];

  float* X     = (float*)d_out;                       // (S, N)
  float* Y     = X + (size_t)SS * NSLOT;              // (S, N)
  float* Start = Y + (size_t)SS * NSLOT;              // (N,)

  unsigned long long* flags  = (unsigned long long*)d_ws;              // 4 KB
  unsigned long long* bmp    = flags + 2 * FPW;                        // 32 planes x 512 u64
  unsigned long long* intadv = bmp + 32 * CWP;                         // 31*GG u64

  k_init<<<128, 256, 0, stream>>>(flags, (unsigned int*)bmp);

  k_steps<<<NBLK, 256, 0, stream>>>(ff, fbk, X, Y, Start, bmp, flags, intadv);
}

// Round 13
// 375.055 us; speedup vs baseline: 1.0473x; 1.0081x over previous
//
#include <hip/hip_runtime.h>
#include <cstdint>

// Problem constants (fixed by setup_inputs: H=480, W=1024, S=32, margin=10, step=4)
#define HH 480
#define WW 1024
#define SS 32
#define HW (HH*WW)              // 491520
#define MARGIN 10
#define STEP 4
#define GYC 116                 // len(arange(10, 471, 4))
#define GXC 252                 // len(arange(10, 1015, 4))
#define GG (GYC*GXC)            // 29232 grid candidates (= 456*64 + 48)
#define NSLOT (2*HH*WW/(STEP*STEP))  // 61440 trajectory slots
#define NBLK (NSLOT/256)        // 240 blocks -> co-resident on 256 CUs
#define CW ((GG+63)/64)         // 457 candidate bitmap words
#define CWP 512                 // padded word count (per-block scan width + plane stride)
#define FPW 256                 // u64 flag entries per parity plane (packed, 8 lines)
#define CPB 122                 // producer cells per block (240*122 >= GG)

// Agent-scope (device-coherent) accessors.
__device__ __forceinline__ unsigned long long aload64(const unsigned long long* p) {
  return __hip_atomic_load(p, __ATOMIC_RELAXED, __HIP_MEMORY_SCOPE_AGENT);
}
__device__ __forceinline__ void astore64(unsigned long long* p, unsigned long long v) {
  __hip_atomic_store(p, v, __ATOMIC_RELAXED, __HIP_MEMORY_SCOPE_AGENT);
}
__device__ __forceinline__ void aor64(unsigned long long* p, unsigned long long v) {
  (void)__hip_atomic_fetch_or(p, v, __ATOMIC_RELAXED, __HIP_MEMORY_SCOPE_AGENT);
}

__device__ __forceinline__ int clampi(int v, int lo, int hi) {
  return v < lo ? lo : (v > hi ? hi : v);
}

// Paired corner load: bilinear footprints always read cols (x0i, x1i) with
// x1i = min(x0i+1, WW-1). One unaligned 8B load at bx = min(x0i, WW-2) gives
// v = (base[row*WW+bx], base[row*WW+bx+1]); then
//   c0 = base[row*WW+x0i] = (x0i==bx) ? v.x : v.y   (x0i=WW-1 -> bx+1)
//   c1 = base[row*WW+x1i] = v.y                      (x1i = bx+1 in ALL cases)
// Values bit-identical to the two scalar loads; halves gather instructions.
__device__ __forceinline__ void ld2(const float* __restrict__ base, int row, int xlo,
                                    float& c0, float& c1) {
  int bx = (xlo < WW - 1) ? xlo : (WW - 2);
  float2 v;
  __builtin_memcpy(&v, base + row * WW + bx, 8);
  c0 = (xlo == bx) ? v.x : v.y;
  c1 = v.y;
}

// ---------------------------------------------------------------------------
// Bilinear footprint at (xs,ys). Identical float ops to the verified kernels.
// ---------------------------------------------------------------------------
struct Bil {
  int x0i, x1i, y0i, y1i;
  int i00, i01, i10, i11;
  float w00, w01, w10, w11;
};

__device__ __forceinline__ Bil mkbil(float xs, float ys) {
#pragma clang fp contract(off)
  float x0 = floorf(xs), y0 = floorf(ys);
  float wx1 = xs - x0, wx0 = 1.0f - wx1;
  float wy1 = ys - y0, wy0 = 1.0f - wy1;
  Bil b;
  b.x0i = clampi((int)x0, 0, WW - 1);
  b.x1i = b.x0i + 1 > WW - 1 ? WW - 1 : b.x0i + 1;
  b.y0i = clampi((int)y0, 0, HH - 1);
  b.y1i = b.y0i + 1 > HH - 1 ? HH - 1 : b.y0i + 1;
  b.i00 = b.y0i * WW + b.x0i; b.i01 = b.y0i * WW + b.x1i;
  b.i10 = b.y1i * WW + b.x0i; b.i11 = b.y1i * WW + b.x1i;
  b.w00 = wy0 * wx0; b.w01 = wy0 * wx1;
  b.w10 = wy1 * wx0; b.w11 = wy1 * wx1;
  return b;
}

// Fwd-bwd consistency bit from pre-gathered backward-flow corner values.
__device__ __forceinline__ float prune_val(float fx, float fy,
    float c00a, float c01a, float c10a, float c11a,
    float c00b, float c01b, float c10b, float c11b, const Bil& t)
{
#pragma clang fp contract(off)
  float bw0 = ((c00a * t.w00 + c01a * t.w01) + c10a * t.w10) + c11a * t.w11;
  float bw1 = ((c00b * t.w00 + c01b * t.w01) + c10b * t.w10) + c11b * t.w11;
  float t0 = fx + bw0, t1 = fy + bw1;
  float diff = sqrtf(t0 * t0 + t1 * t1);
  float magf = sqrtf(fx * fx + fy * fy);
  float magb = sqrtf(bw0 * bw0 + bw1 * bw1);
  float mag = 0.5f * (magf + magb);
  return (diff <= 0.01f * mag + 0.1f) ? 1.0f : 0.0f;
}

// Integer-cell first-transition outcome {xt,yt,choose} packed as u64
// (choose encoded as yt<0). Bit-identical to the verified mode-2 path.
__device__ __forceinline__ unsigned long long make_intadv(
    int pix, int piy, float fx, float fy, const float* __restrict__ bks)
{
#pragma clang fp contract(off)
  float xt = (float)pix + fx, yt = (float)piy + fy;
  Bil Bt = mkbil(xt, yt);
  const float* b0p = bks;
  const float* b1p = bks + HW;
  float o = prune_val(fx, fy,
                      b0p[Bt.i00], b0p[Bt.i01], b0p[Bt.i10], b0p[Bt.i11],
                      b1p[Bt.i00], b1p[Bt.i01], b1p[Bt.i10], b1p[Bt.i11], Bt);
  bool marg = (xt > (float)MARGIN) && (yt > (float)MARGIN) &&
              (xt < (float)(WW - MARGIN)) && (yt < (float)(HH - MARGIN));
  bool ch = marg && (o > 0.5f);
  unsigned lo = __float_as_uint(ch ? xt : 0.0f);
  unsigned hi = __float_as_uint(ch ? yt : -1.0f);
  return ((unsigned long long)hi << 32) | (unsigned long long)lo;
}

// ---------------------------------------------------------------------------
// K1: persistent scan, ONE grid barrier per step. Round-13 = verified
// round-12 kernel + two independent micro-changes:
//  * NO k_init: flags+bmp are zeroed by one hipMemsetAsync. Zeroed flags =
//    "all blocks arrived at epoch 0" (valid start). Pad entries (240..255)
//    are never read: poll index 3 is clamped to NBLK-1 (duplicate min
//    entries harmless); its rank/total contributions are guarded by the
//    UNCLAMPED index so nothing is double-counted.
//  * DEFERRED X/Y row stores: row kept in rx/ry, stored right after the
//    arrival store (inside the wait window) instead of at CD tail where it
//    sat on the next step's pre-arrival vmcnt drain.
// ---------------------------------------------------------------------------
__global__ __launch_bounds__(256, 1) void k_steps(
    const float* __restrict__ ff, const float* __restrict__ fbk,
    float* __restrict__ X, float* __restrict__ Y, float* __restrict__ Start,
    unsigned long long* __restrict__ bmp, unsigned long long* __restrict__ flags,
    unsigned long long* __restrict__ intadv)
{
#pragma clang fp contract(off)
  const int b = blockIdx.x;
  const int lane = threadIdx.x & 63;
  const int wv = threadIdx.x >> 6;                   // wave-in-block 0..3
  const int slot = ((wv * NBLK + b) << 6) | lane;    // wave-permuted slot id
  const unsigned long long ltmask = (1ull << lane) - 1ull;

  __shared__ unsigned long long wds[CWP];   // free-candidate bitmap (4 KB)
  __shared__ unsigned int pref[CWP];        // inclusive popcount prefix (2 KB)
  __shared__ int wsum[4];                   // scan partials
  __shared__ int wcnt[2][4];                // per-wave dead counts (parity)
  __shared__ int ps4[4];                    // per-wave lower-rank totals

  // Consumer slot state. mode: 0 dead, 1 pipelined, 2 integer-pos (pa64 valid).
  float x = 0.f, y = 0.f, st = -1.f;
  int mode = 0;
  float pf0 = 0.f, pf1 = 0.f, pf2 = 0.f, pf3 = 0.f;   // f0 at taps 00,01,10,11
  float pf4 = 0.f, pf5 = 0.f, pf6 = 0.f, pf7 = 0.f;   // f1 at taps 00,01,10,11
  float pb[32];                                        // b corner values, 8/tap
  float pxt = 0.f, pyt = 0.f;                          // advected candidate
  bool  pmarg = false;
  unsigned long long pa64 = (unsigned long long)0xBF800000u << 32;  // yt=-1

  // Producer identity (decoupled from slot): even threads, ~30 cells/wave.
  const int pj = threadIdx.x >> 1;
  const int pcell = b * CPB + pj;
  const bool prod = ((threadIdx.x & 1) == 0) && (pj < CPB) && (pcell < GG);
  int pix = 0, piy = 0, pp = 0;
  float fNx = 0.f, fNy = 0.f;      // f(s+4) pair (issued last step)
  float fCx = 0.f, fCy = 0.f;      // f(s+3) pair (arrived)
  float bC0 = 0.f, bC1 = 0.f, bC2 = 0.f, bC3 = 0.f;   // b(s+3) corners
  float bC4 = 0.f, bC5 = 0.f, bC6 = 0.f, bC7 = 0.f;

  // ---- Slot prologue: initial alive slots compute their own A(0) input ----
  if (slot < GG) {
    int ii = slot / GXC, jj = slot - ii * GXC;
    int ix = MARGIN + STEP * jj, iy = MARGIN + STEP * ii;
    x = (float)ix; y = (float)iy;
    st = 0.f; mode = 2;
    int p0_ = iy * WW + ix;
    float f0x = ff[p0_], f0y = ff[HW + p0_];
    pa64 = make_intadv(ix, iy, f0x, f0y, fbk);
  }
  X[slot] = x; Y[slot] = y;   // row 0
  float rx = x, ry = y;       // deferred-store copy of the latest row

  // ---- Producer prologue: bootstrap intadv[1..2] + b(3)/f(4) in flight ----
  if (prod) {
    int ii = pcell / GXC, jj = pcell - ii * GXC;
    pix = MARGIN + STEP * jj; piy = MARGIN + STEP * ii;
    pp = piy * WW + pix;
    float f1x = ff[(size_t)1 * 2 * HW + pp], f1y = ff[(size_t)1 * 2 * HW + HW + pp];
    float f2x = ff[(size_t)2 * 2 * HW + pp], f2y = ff[(size_t)2 * 2 * HW + HW + pp];
    float f3x = ff[(size_t)3 * 2 * HW + pp], f3y = ff[(size_t)3 * 2 * HW + HW + pp];
    fNx = ff[(size_t)4 * 2 * HW + pp];       fNy = ff[(size_t)4 * 2 * HW + HW + pp];
    astore64(&intadv[(size_t)1 * GG + pcell],
             make_intadv(pix, piy, f1x, f1y, fbk + (size_t)1 * 2 * HW));
    astore64(&intadv[(size_t)2 * GG + pcell],
             make_intadv(pix, piy, f2x, f2y, fbk + (size_t)2 * 2 * HW));
    {  // issue b(3) corners; consumed at overlap(0)
      float xt = (float)pix + f3x, yt = (float)piy + f3y;
      Bil Bt = mkbil(xt, yt);
      const float* bb0 = fbk + (size_t)3 * 2 * HW;
      const float* bb1 = bb0 + HW;
      ld2(bb0, Bt.y0i, Bt.x0i, bC0, bC1);
      ld2(bb0, Bt.y1i, Bt.x0i, bC2, bC3);
      ld2(bb1, Bt.y0i, Bt.x0i, bC4, bC5);
      ld2(bb1, Bt.y1i, Bt.x0i, bC6, bC7);
      fCx = f3x; fCy = f3y;
    }
  }

// Issue the 16 paired b-corner loads for tap tt (consumed next step's A).
#define ISSUE_TAP(tt, TXI, TYI, FX, FY) do { \
    Bil Bt = mkbil((float)P.TXI + (FX), (float)P.TYI + (FY)); \
    ld2(b0n, Bt.y0i, Bt.x0i, pb[(tt)*8+0], pb[(tt)*8+1]); \
    ld2(b0n, Bt.y1i, Bt.x0i, pb[(tt)*8+2], pb[(tt)*8+3]); \
    ld2(b1n, Bt.y0i, Bt.x0i, pb[(tt)*8+4], pb[(tt)*8+5]); \
    ld2(b1n, Bt.y1i, Bt.x0i, pb[(tt)*8+6], pb[(tt)*8+7]); \
  } while (0)

// Recompute the identical footprint and fold pre-loaded values into the bit.
#define PRUNE_TAP(tt, TXI, TYI, FX, FY, OUT) do { \
    Bil Bt = mkbil((float)P.TXI + (FX), (float)P.TYI + (FY)); \
    OUT = prune_val((FX), (FY), \
                    pb[(tt)*8+0], pb[(tt)*8+1], pb[(tt)*8+2], pb[(tt)*8+3], \
                    pb[(tt)*8+4], pb[(tt)*8+5], pb[(tt)*8+6], pb[(tt)*8+7], Bt); \
  } while (0)

  for (int s = 0; s < SS - 1; ++s) {
    unsigned long long* pl = bmp + (size_t)(s + 1) * CWP;   // this step's bit-plane

    // ---- Phase A: LOAD-FREE prune decision + bit-plane marks -------------
    bool moved = false;
    if (mode == 1) {
      Bil P = mkbil(x, y);
      float o0, o1, o2, o3;
      PRUNE_TAP(0, x0i, y0i, pf0, pf4, o0);
      PRUNE_TAP(1, x1i, y0i, pf1, pf5, o1);
      PRUNE_TAP(2, x0i, y1i, pf2, pf6, o2);
      PRUNE_TAP(3, x1i, y1i, pf3, pf7, o3);
      float fbv = ((o0 * P.w00 + o1 * P.w01) + o2 * P.w10) + o3 * P.w11;
      if (pmarg && fbv > 0.5f) {
        x = pxt; y = pyt;
        moved = true;
      } else { st = -1.f; x = 0.f; y = 0.f; mode = 0; }
    } else if (mode == 2) {
      float axt = __uint_as_float((unsigned)pa64);
      float ayt = __uint_as_float((unsigned)(pa64 >> 32));
      if (ayt >= 0.0f) {                      // choose
        x = axt; y = ayt; mode = 1;
        moved = true;
      } else { st = -1.f; x = 0.f; y = 0.f; mode = 0; }
    }
    if (moved) {
      int oy = (int)y, ox = (int)x;   // trunc == floor (positive)
      int i0 = ((oy - (MARGIN + 2) + 4099) >> 2) - 1024;  // ceil((oy-12)/4)
      int i1 = ((oy - (MARGIN - 2) + 4096) >> 2) - 1024;  // floor((oy-8)/4)
      int j0 = ((ox - (MARGIN + 2) + 4099) >> 2) - 1024;
      int j1 = ((ox - (MARGIN - 2) + 4096) >> 2) - 1024;
      if (i0 < 0) i0 = 0; if (i1 > GYC - 1) i1 = GYC - 1;
      if (j0 < 0) j0 = 0; if (j1 > GXC - 1) j1 = GXC - 1;
      for (int i = i0; i <= i1; ++i) {        // <=2 rows, <=2 adjacent bits
        int g0 = i * GXC + j0;
        int w = g0 >> 6, bo = g0 & 63;
        unsigned long long m = ((j1 > j0) ? 3ull : 1ull) << bo;  // bit63 ovfl drops
        aor64(&pl[w], m);
        if (bo == 63 && j1 > j0) aor64(&pl[w + 1], 1ull);
      }
    }
    unsigned long long smask = __ballot(st < 0.0f);
    if (lane == 0) wcnt[s & 1][wv] = (int)__popcll(smask);

    // ---- Barrier arrival: entry sync drains the marks, then one store ----
    unsigned long long* fb = flags + (s & 1) * FPW;
    const int epoch = s + 1;
    __syncthreads();
    if (threadIdx.x == 0) {
      const int* wc = wcnt[s & 1];
      unsigned cpack = (unsigned)wc[0] | ((unsigned)wc[1] << 8)
                     | ((unsigned)wc[2] << 16) | ((unsigned)wc[3] << 24);
      astore64(&fb[b],
               ((unsigned long long)(unsigned)epoch << 32) | (unsigned long long)cpack);
    }

    // ---- Deferred output store of row s (saved last iteration) -----------
    X[(size_t)s * NSLOT + slot] = rx;   // s=0 re-stores row 0: harmless dup
    Y[(size_t)s * NSLOT + slot] = ry;

    // ---- Wait-window overlap (f-issue / producer / consume) --------------
    // (1) issue the 4 f(s+1) paired loads (non-blocking)
    const bool dopipe = (mode == 1 && s < SS - 2);
    Bil P;
    const float* f0n = ff + (size_t)(s + 1) * 2 * HW;
    const float* f1n = f0n + HW;
    if (dopipe) {
      P = mkbil(x, y);
      ld2(f0n, P.y0i, P.x0i, pf0, pf1);
      ld2(f0n, P.y1i, P.x0i, pf2, pf3);
      ld2(f1n, P.y0i, P.x0i, pf4, pf5);
      ld2(f1n, P.y1i, P.x0i, pf6, pf7);
    }
    // (2) producer work rides under the f-load latency
    if (prod) {
      if (s <= SS - 5) {                       // k = s+3 <= 30
        float xt = (float)pix + fCx, yt = (float)piy + fCy;
        Bil Bt = mkbil(xt, yt);
        float o = prune_val(fCx, fCy, bC0, bC1, bC2, bC3, bC4, bC5, bC6, bC7, Bt);
        bool marg = (xt > (float)MARGIN) && (yt > (float)MARGIN) &&
                    (xt < (float)(WW - MARGIN)) && (yt < (float)(HH - MARGIN));
        bool ch = marg && (o > 0.5f);
        unsigned lo = __float_as_uint(ch ? xt : 0.0f);
        unsigned hi = __float_as_uint(ch ? yt : -1.0f);
        astore64(&intadv[(size_t)(s + 3) * GG + pcell],
                 ((unsigned long long)hi << 32) | (unsigned long long)lo);
      }
      if (s <= SS - 6) {                       // issue b(s+4), f(s+4) arrived
        float xt = (float)pix + fNx, yt = (float)piy + fNy;
        Bil Bt = mkbil(xt, yt);
        const float* bb0 = fbk + (size_t)(s + 4) * 2 * HW;
        const float* bb1 = bb0 + HW;
        ld2(bb0, Bt.y0i, Bt.x0i, bC0, bC1);
        ld2(bb0, Bt.y1i, Bt.x0i, bC2, bC3);
        ld2(bb1, Bt.y0i, Bt.x0i, bC4, bC5);
        ld2(bb1, Bt.y1i, Bt.x0i, bC6, bC7);
        fCx = fNx; fCy = fNy;
      }
      if (s <= SS - 7) {                       // issue static f(s+5)
        const float* fp_ = ff + (size_t)(s + 5) * 2 * HW;
        fNx = fp_[pp]; fNy = fp_[HW + pp];
      }
    }
    // (3) consume pf: advect + issue the 16 b(s+1) paired loads
    if (dopipe) {
      float u_ = ((pf0 * P.w00 + pf1 * P.w01) + pf2 * P.w10) + pf3 * P.w11;
      float v_ = ((pf4 * P.w00 + pf5 * P.w01) + pf6 * P.w10) + pf7 * P.w11;
      pxt = x + u_; pyt = y + v_;
      pmarg = (pxt > (float)MARGIN) && (pyt > (float)MARGIN) &&
              (pxt < (float)(WW - MARGIN)) && (pyt < (float)(HH - MARGIN));
      const float* b0n = fbk + (size_t)(s + 1) * 2 * HW;
      const float* b1n = b0n + HW;
      ISSUE_TAP(0, x0i, y0i, pf0, pf4);
      ISSUE_TAP(1, x1i, y0i, pf1, pf5);
      ISSUE_TAP(2, x0i, y1i, pf2, pf6);
      ISSUE_TAP(3, x1i, y1i, pf3, pf7);
    }

    // ---- Poll (wave 0): 4 loads/lane (idx3 clamped; pads never read) -----
    if (threadIdx.x < 64) {
      const int i3 = lane + 192;
      const int i3c = (i3 < NBLK) ? i3 : (NBLK - 1);
      unsigned long long v0, v1, v2, v3;
      for (;;) {
        v0 = aload64(&fb[lane      ]);
        v1 = aload64(&fb[lane +  64]);
        v2 = aload64(&fb[lane + 128]);
        v3 = aload64(&fb[i3c       ]);
        unsigned m0 = (unsigned)(v0 >> 32), m1 = (unsigned)(v1 >> 32);
        unsigned m2 = (unsigned)(v2 >> 32), m3 = (unsigned)(v3 >> 32);
        unsigned mn = m0 < m1 ? m0 : m1;
        unsigned mn2 = m2 < m3 ? m2 : m3;
        mn = mn < mn2 ? mn : mn2;
        for (int o = 32; o > 0; o >>= 1) {
          unsigned t = (unsigned)__shfl_xor((int)mn, o, 64);
          mn = mn < t ? mn : t;
        }
        if ((int)mn >= epoch) break;
        __builtin_amdgcn_s_sleep(1);
      }
      auto up = [](unsigned long long f) -> unsigned long long {
        unsigned c = (unsigned)f;
        return (unsigned long long)(c & 0xFFu)
             | ((unsigned long long)((c >>  8) & 0xFFu) << 16)
             | ((unsigned long long)((c >> 16) & 0xFFu) << 32)
             | ((unsigned long long)((c >> 24) & 0xFFu) << 48);
      };
      unsigned long long u0 = up(v0), u1 = up(v1), u2 = up(v2);
      unsigned long long u3 = (i3 < NBLK) ? up(v3) : 0ull;   // guard UNCLAMPED idx
      unsigned long long F = u0 + u1 + u2 + u3;
      unsigned long long Pp = (lane       < b ? u0 : 0ull)
                            + (lane +  64 < b ? u1 : 0ull)
                            + (lane + 128 < b ? u2 : 0ull)
                            + (i3         < b ? u3 : 0ull);
      for (int o = 32; o > 0; o >>= 1) {
        unsigned flo = (unsigned)F, fhi = (unsigned)(F >> 32);
        unsigned plo = (unsigned)Pp, phi = (unsigned)(Pp >> 32);
        unsigned flo2 = (unsigned)__shfl_xor((int)flo, o, 64);
        unsigned fhi2 = (unsigned)__shfl_xor((int)fhi, o, 64);
        unsigned plo2 = (unsigned)__shfl_xor((int)plo, o, 64);
        unsigned phi2 = (unsigned)__shfl_xor((int)phi, o, 64);
        F  += ((unsigned long long)fhi2 << 32) | flo2;
        Pp += ((unsigned long long)phi2 << 32) | plo2;
      }
      if (lane == 0) {
        int f0 = (int)(F & 0xFFFF), f1 = (int)((F >> 16) & 0xFFFF), f2 = (int)((F >> 32) & 0xFFFF);
        int p0 = (int)(Pp & 0xFFFF), p1 = (int)((Pp >> 16) & 0xFFFF);
        int p2 = (int)((Pp >> 32) & 0xFFFF), p3 = (int)((Pp >> 48) & 0xFFFF);
        ps4[0] = p0;
        ps4[1] = f0 + p1;
        ps4[2] = f0 + f1 + p2;
        ps4[3] = f0 + f1 + f2 + p3;
      }
    }
    __syncthreads();
    int ps = ps4[wv];

    // ---- Phase CD: direct masked bit-plane load + prefix + births --------
    {
      int t = threadIdx.x;
      int e0 = 2 * t, e1 = 2 * t + 1;
      unsigned long long m0 = 0ull, m1 = 0ull;
      if (e0 < CW) m0 = ~aload64(&pl[e0]);            // free = NOT occupied
      if (e1 < CW) m1 = ~aload64(&pl[e1]);
      if (e0 == CW - 1) m0 &= (1ull << 48) - 1ull;    // tail: 48 valid cells
      if (e1 == CW - 1) m1 &= (1ull << 48) - 1ull;
      wds[e0] = m0; wds[e1] = m1;
      int p0 = __popcll(m0), p1 = __popcll(m1);
      int v = p0 + p1;
      for (int o = 1; o < 64; o <<= 1) {
        int uu = __shfl_up(v, o, 64);
        if (lane >= o) v += uu;
      }
      if (lane == 63) wsum[wv] = v;
      __syncthreads();
      int base = 0;
      for (int j2 = 0; j2 < wv; ++j2) base += wsum[j2];
      pref[e0] = (unsigned int)(base + v - p1);
      pref[e1] = (unsigned int)(base + v);
      __syncthreads();
    }
    int tc = (int)pref[CWP - 1];              // total free candidates

    if (st < 0.0f) {
      int r = ps + (int)__popcll(smask & ltmask);
      if (r < tc) {                  // r < min(num_cand, num_free) <=> r < num_cand
        int k = 0;
        for (int bb = 256; bb >= 1; bb >>= 1) {
          int nk = k + bb;
          if (nk <= CWP - 1 && (int)pref[nk - 1] <= r) k = nk;
        }
        int j = r - (k ? (int)pref[k - 1] : 0);
        unsigned long long m = wds[k];
        int lo = 0;                  // position of the (j+1)-th set bit
        for (int bb = 32; bb >= 1; bb >>= 1) {
          int nb2 = lo + bb;
          unsigned long long mask = (nb2 >= 64) ? ~0ull : ((1ull << nb2) - 1ull);
          if (__popcll(m & mask) <= j) lo = nb2;
        }
        int g = k * 64 + lo;
        int ii = g / GXC, jj = g - ii * GXC;
        x = (float)(MARGIN + STEP * jj);
        y = (float)(MARGIN + STEP * ii);
        st = (float)(s + 1);
        mode = 2;
        if (s < SS - 2)              // at s=30 there is no A(31): skip the load
          pa64 = aload64(&intadv[(size_t)(s + 1) * GG + g]);   // in flight to A(s+1)
      }
    }
    rx = x; ry = y;   // row s+1 values; stored after next iteration's arrival
    // no trailing __syncthreads: wcnt is parity-double-buffered, and wds/pref
    // rewrites happen only after the next step's post-poll __syncthreads.
  }

#undef ISSUE_TAP
#undef PRUNE_TAP

  X[(size_t)(SS - 1) * NSLOT + slot] = rx;   // final row (31)
  Y[(size_t)(SS - 1) * NSLOT + slot] = ry;
  Start[slot] = st;
}

// ---------------------------------------------------------------------------
extern "C" void kernel_launch(void* const* d_in, const int* in_sizes, int n_in,
                              void* d_out, int out_size, void* d_ws, size_t ws_size,
                              hipStream_t stream) {
  const float* ff  = (const float*)d_in[0];   // (1,S,2,H,W)
  const float* fbk = (const float*)d_in[1];

  float* X     = (float*)d_out;                       // (S, N)
  float* Y     = X + (size_t)SS * NSLOT;              // (S, N)
  float* Start = Y + (size_t)SS * NSLOT;              // (N,)

  unsigned long long* flags  = (unsigned long long*)d_ws;              // 4 KB
  unsigned long long* bmp    = flags + 2 * FPW;                        // 32 planes x 512 u64
  unsigned long long* intadv = bmp + 32 * CWP;                         // 31*GG u64

  // Zeroed flags = valid initial barrier state (epoch 0, zero counts);
  // zeroed bmp = all planes unoccupied. Replaces the k_init launch.
  (void)hipMemsetAsync(d_ws, 0, (2 * FPW + 32 * CWP) * sizeof(unsigned long long),
                       stream);

  k_steps<<<NBLK, 256, 0, stream>>>(ff, fbk, X, Y, Start, bmp, flags, intadv);
}